// Round 17
// baseline (199.911 us; speedup 1.0000x reference)
//
#include <hip/hip_runtime.h>

// 2-layer LSTM, B=4096, S=512, F=8, H=10 + FC(10->1) on last step.
// R16: R10's per-step code at HIGHER COVERAGE + uniform grid:
//  - 2 elements/wave (20-lane groups, lanes 0-39) -> 4096 waves = exactly
//    4 waves/SIMD (R10: 2.67). Same stream shape, more chain coverage.
//  - 1024 blocks x 256 thr = exactly 4 blocks/CU, no imbalance, no pad
//    elements (all e<4096 guards deleted).
//  - L0 x addressing: bumped pointer (xr += 32 per 16 steps) + compile-time
//    immediate offsets; per-step clamp deleted (last iter peeled, late
//    refills skipped -- their targets are never consumed).
// Per-step scheme (R10, proven): lane l20 owns gate rows rA=l20, rB=20+l20;
// unified act alpha*rcp(1+exp2(-a))+beta; ig lane-local on i/g lanes; sf,so
// pulled from lane+10 via 2 bperms; c/h on i/g lanes; distance-1 x-dot
// software pipeline; 16-slot h0 buffer; barrier every 8 steps.

typedef __fp16 v2h __attribute__((ext_vector_type(2)));
typedef __fp16 v8h __attribute__((ext_vector_type(8)));
struct h4 { v2h a, b, c, d; };

#define L2E 1.4426950408889634f

__device__ __forceinline__ v2h pkh(float a, float b) {
    return __builtin_amdgcn_cvt_pkrtz(a, b);
}
__device__ __forceinline__ float bpermf(int baddr, float v) {
    int r = __builtin_amdgcn_ds_bpermute(baddr, __builtin_bit_cast(int, v));
    return __builtin_bit_cast(float, r);
}

#define SIGM(a)  __builtin_amdgcn_rcpf(1.0f + __builtin_amdgcn_exp2f(-(a)))
#define TANHP(a) fmaf(-2.0f, __builtin_amdgcn_rcpf(1.0f + __builtin_amdgcn_exp2f(a)), 1.0f)
#define DOT2(acc, w, v) (acc) = __builtin_amdgcn_fdot2((w), (v), (acc), false)

// TBAA-safe packed row read (PTR __fp16*, 16B aligned): 10 halves
#define READROW(PTR, H)                                                      \
    { v8h w0_ = *(const v8h*)(PTR);                                          \
      v2h w1_ = *(const v2h*)((PTR) + 8);                                    \
      h4 q_ = __builtin_bit_cast(h4, w0_);                                   \
      H[0]=q_.a; H[1]=q_.b; H[2]=q_.c; H[3]=q_.d; H[4]=w1_; }

__global__ __launch_bounds__(256, 4)
void lstm2_r16(const float* __restrict__ x,
               const float* __restrict__ hid,
               const float* __restrict__ cel,
               const float* __restrict__ Wih0, const float* __restrict__ Whh0,
               const float* __restrict__ bih0, const float* __restrict__ bhh0,
               const float* __restrict__ Wih1, const float* __restrict__ Whh1,
               const float* __restrict__ bih1, const float* __restrict__ bhh1,
               const float* __restrict__ Wfc,  const float* __restrict__ bfc,
               float* __restrict__ out)
{
    __shared__ __attribute__((aligned(16))) __fp16 h0buf[16][4][24]; // 3 KB
    __shared__ __attribute__((aligned(16))) __fp16 h1buf[4][24];
    __shared__ float fcb[4][10];

    const int tid  = threadIdx.x;
    const int lane = tid & 63;
    const int uwid = __builtin_amdgcn_readfirstlane(tid >> 6);
    int grp = lane / 20;
    int l20 = lane - grp * 20;
    if (lane >= 40) { grp = 1; l20 = 19; }   // idle lanes duplicate lane 39
    const int  ju       = (l20 < 10) ? l20 : l20 - 10;  // unit index
    const bool unitlane = (l20 < 10) && (lane < 40);
    const int  eIw = (uwid & 1) * 2 + grp;   // element in block, 0..3
    const int  e   = blockIdx.x * 4 + eIw;   // 1024*4 = 4096 exact
    const int  baddr = ((l20 < 10) ? (lane + 10) : lane) * 4;  // bpermute src

    const float alpha2 = (l20 < 10) ? 2.0f : 1.0f;   // rowB act: tanh vs sigma
    const float beta2  = (l20 < 10) ? -1.0f : 0.0f;
    const float scB    = (l20 < 10) ? 2.0f * L2E : L2E;
    const int   rA = l20, rB = 20 + l20;

    if (uwid < 2) {
        // ================= LAYER-0 (producer) waves =================
        v2h wxA[4], wxB[4], whA[5], whB[5];
        #pragma unroll
        for (int k = 0; k < 4; ++k) {
            wxA[k] = pkh(Wih0[rA*8+2*k]*L2E, Wih0[rA*8+2*k+1]*L2E);
            wxB[k] = pkh(Wih0[rB*8+2*k]*scB, Wih0[rB*8+2*k+1]*scB);
        }
        #pragma unroll
        for (int k = 0; k < 5; ++k) {
            whA[k] = pkh(Whh0[rA*10+2*k]*L2E, Whh0[rA*10+2*k+1]*L2E);
            whB[k] = pkh(Whh0[rB*10+2*k]*scB, Whh0[rB*10+2*k+1]*scB);
        }
        const float bA = (bih0[rA] + bhh0[rA]) * L2E;
        const float bB = (bih0[rB] + bhh0[rB]) * scB;

        v2h hv[5];
        #pragma unroll
        for (int k = 0; k < 5; ++k) hv[k] = pkh(hid[e*10+2*k], hid[e*10+2*k+1]);
        float cc = cel[e * 10 + ju];
        float hj = 0.0f;

        __fp16* const wbase = &h0buf[0][eIw][0];   // slot stride 96 halves
        __fp16* const wlane = wbase + l20;

        const float4* __restrict__ xp4 = reinterpret_cast<const float4*>(x + (size_t)e * 4096);
        float4 xb0[2], xb1[2], xb2[2], xb3[2];
        xb0[0]=xp4[0]; xb0[1]=xp4[1];  xb1[0]=xp4[2]; xb1[1]=xp4[3];
        xb2[0]=xp4[4]; xb2[1]=xp4[5];  xb3[0]=xp4[6]; xb3[1]=xp4[7];

        float axA[2], axB[2];
        // prologue: ax(step 0) from xb0, then refill xb0 <- x[4]
        {
            v2h x0=pkh(xb0[0].x,xb0[0].y), x1=pkh(xb0[0].z,xb0[0].w);
            v2h x2=pkh(xb0[1].x,xb0[1].y), x3=pkh(xb0[1].z,xb0[1].w);
            xb0[0]=xp4[8]; xb0[1]=xp4[9];
            float nA=bA, nB=bB;
            DOT2(nA,wxA[0],x0); DOT2(nB,wxB[0],x0);
            DOT2(nA,wxA[1],x1); DOT2(nB,wxB[1],x1);
            DOT2(nA,wxA[2],x2); DOT2(nB,wxB[2],x2);
            DOT2(nA,wxA[3],x3); DOT2(nB,wxB[3],x3);
            axA[0]=nA; axB[0]=nB;
        }

// L0 step s = tb+S: filler = ax(s+1) from XB; refill XB <- xr[2*(S+5)]
// (compile-time imm off bumped xr = xp4 + 2*tb); current uses ax[PC];
// write h slot S; packed TBAA-safe readback.
#define L0STEP(S, XB, DOREF, PC, PN)                                         \
        {                                                                    \
            v2h x0=pkh(XB[0].x,XB[0].y), x1=pkh(XB[0].z,XB[0].w);            \
            v2h x2=pkh(XB[1].x,XB[1].y), x3=pkh(XB[1].z,XB[1].w);            \
            if (DOREF) { XB[0]=xr[2*((S)+5)]; XB[1]=xr[2*((S)+5)+1]; }       \
            float nA=bA, nB=bB;                                              \
            DOT2(nA,wxA[0],x0); DOT2(nB,wxB[0],x0);                          \
            DOT2(nA,wxA[1],x1); DOT2(nB,wxB[1],x1);                          \
            DOT2(nA,wxA[2],x2); DOT2(nB,wxB[2],x2);                          \
            DOT2(nA,wxA[3],x3); DOT2(nB,wxB[3],x3);                          \
            axA[PN]=nA; axB[PN]=nB;                                          \
            float aA=axA[PC], aB=axB[PC];                                    \
            DOT2(aA,whA[0],hv[0]); DOT2(aB,whB[0],hv[0]);                    \
            DOT2(aA,whA[1],hv[1]); DOT2(aB,whB[1],hv[1]);                    \
            DOT2(aA,whA[2],hv[2]); DOT2(aB,whB[2],hv[2]);                    \
            DOT2(aA,whA[3],hv[3]); DOT2(aB,whB[3],hv[3]);                    \
            DOT2(aA,whA[4],hv[4]); DOT2(aB,whB[4],hv[4]);                    \
            float r1 = SIGM(aA);                                             \
            float r2 = __builtin_amdgcn_rcpf(1.0f + __builtin_amdgcn_exp2f(-aB)); \
            float act2 = fmaf(alpha2, r2, beta2);                            \
            float ig = r1 * act2;                                            \
            float sf = bpermf(baddr, r1);                                    \
            float so = bpermf(baddr, act2);                                  \
            cc = fmaf(sf, cc, ig);                                           \
            hj = so * TANHP((2.0f*L2E) * cc);                                \
            wlane[(S)*96] = (__fp16)hj;                                      \
            READROW(wbase + (S)*96, hv)                                      \
        }

        const float4* __restrict__ xr = xp4;
        for (int it = 0; it < 31; ++it) {
            L0STEP(0,  xb1, 1, 0, 1)
            L0STEP(1,  xb2, 1, 1, 0)
            L0STEP(2,  xb3, 1, 0, 1)
            L0STEP(3,  xb0, 1, 1, 0)
            L0STEP(4,  xb1, 1, 0, 1)
            L0STEP(5,  xb2, 1, 1, 0)
            L0STEP(6,  xb3, 1, 0, 1)
            L0STEP(7,  xb0, 1, 1, 0)
            __syncthreads();
            L0STEP(8,  xb1, 1, 0, 1)
            L0STEP(9,  xb2, 1, 1, 0)
            L0STEP(10, xb3, 1, 0, 1)
            L0STEP(11, xb0, 1, 1, 0)
            L0STEP(12, xb1, 1, 0, 1)
            L0STEP(13, xb2, 1, 1, 0)
            L0STEP(14, xb3, 1, 0, 1)
            L0STEP(15, xb0, 1, 1, 0)
            __syncthreads();
            xr += 32;
        }
        // peeled it=31 (steps 496..511): refills only for t=501..511
        L0STEP(0,  xb1, 1, 0, 1)
        L0STEP(1,  xb2, 1, 1, 0)
        L0STEP(2,  xb3, 1, 0, 1)
        L0STEP(3,  xb0, 1, 1, 0)
        L0STEP(4,  xb1, 1, 0, 1)
        L0STEP(5,  xb2, 1, 1, 0)
        L0STEP(6,  xb3, 1, 0, 1)
        L0STEP(7,  xb0, 1, 1, 0)
        __syncthreads();
        L0STEP(8,  xb1, 1, 0, 1)
        L0STEP(9,  xb2, 1, 1, 0)
        L0STEP(10, xb3, 1, 0, 1)
        L0STEP(11, xb0, 0, 1, 0)
        L0STEP(12, xb1, 0, 0, 1)
        L0STEP(13, xb2, 0, 1, 0)
        L0STEP(14, xb3, 0, 0, 1)
        L0STEP(15, xb0, 0, 1, 0)
        __syncthreads();
#undef L0STEP

        __syncthreads();   // pair with L1's FC epilogue barrier
        if (unitlane) {
            out[4096          + e * 10 + ju] = hj;   // h0_T
            out[4096 + 81920  + e * 10 + ju] = cc;   // c0_T
        }

    } else {
        // ================= LAYER-1 (consumer) waves =================
        v2h wiA[5], wiB[5], whA[5], whB[5];
        #pragma unroll
        for (int k = 0; k < 5; ++k) {
            wiA[k] = pkh(Wih1[rA*10+2*k]*L2E, Wih1[rA*10+2*k+1]*L2E);
            wiB[k] = pkh(Wih1[rB*10+2*k]*scB, Wih1[rB*10+2*k+1]*scB);
            whA[k] = pkh(Whh1[rA*10+2*k]*L2E, Whh1[rA*10+2*k+1]*L2E);
            whB[k] = pkh(Whh1[rB*10+2*k]*scB, Whh1[rB*10+2*k+1]*scB);
        }
        const float bA = (bih1[rA] + bhh1[rA]) * L2E;
        const float bB = (bih1[rB] + bhh1[rB]) * scB;
        const float wfc = Wfc[ju];

        v2h hv[5];
        #pragma unroll
        for (int k = 0; k < 5; ++k) hv[k] = pkh(hid[40960+e*10+2*k], hid[40960+e*10+2*k+1]);
        float cc = cel[40960 + e * 10 + ju];
        float hj = 0.0f;

        const __fp16* const rbase = &h0buf[0][eIw][0];   // slot stride 96 halves
        __fp16* const h1w  = &h1buf[eIw][0];
        __fp16* const h1wl = h1w + l20;

        float axA[2], axB[2];

// input-dots (bias + 5 dots x2) for slot S -> ax parity P
#define L1PRE(S, P)                                                          \
        {                                                                    \
            v2h pr[5];                                                       \
            READROW(rbase + (S)*96, pr)                                      \
            float nA=bA, nB=bB;                                              \
            DOT2(nA,wiA[0],pr[0]); DOT2(nB,wiB[0],pr[0]);                    \
            DOT2(nA,wiA[1],pr[1]); DOT2(nB,wiB[1],pr[1]);                    \
            DOT2(nA,wiA[2],pr[2]); DOT2(nB,wiB[2],pr[2]);                    \
            DOT2(nA,wiA[3],pr[3]); DOT2(nB,wiB[3],pr[3]);                    \
            DOT2(nA,wiA[4],pr[4]); DOT2(nB,wiB[4],pr[4]);                    \
            axA[P]=nA; axB[P]=nB;                                            \
        }

// current step using ax parity PC: h-dots, acts, c/h, h1 write+readback
#define L1CORE(PC)                                                           \
        {                                                                    \
            float aA=axA[PC], aB=axB[PC];                                    \
            DOT2(aA,whA[0],hv[0]); DOT2(aB,whB[0],hv[0]);                    \
            DOT2(aA,whA[1],hv[1]); DOT2(aB,whB[1],hv[1]);                    \
            DOT2(aA,whA[2],hv[2]); DOT2(aB,whB[2],hv[2]);                    \
            DOT2(aA,whA[3],hv[3]); DOT2(aB,whB[3],hv[3]);                    \
            DOT2(aA,whA[4],hv[4]); DOT2(aB,whB[4],hv[4]);                    \
            float r1 = SIGM(aA);                                             \
            float r2 = __builtin_amdgcn_rcpf(1.0f + __builtin_amdgcn_exp2f(-aB)); \
            float act2 = fmaf(alpha2, r2, beta2);                            \
            float ig = r1 * act2;                                            \
            float sf = bpermf(baddr, r1);                                    \
            float so = bpermf(baddr, act2);                                  \
            cc = fmaf(sf, cc, ig);                                           \
            hj = so * TANHP((2.0f*L2E) * cc);                                \
            h1wl[0] = (__fp16)hj;                                            \
            READROW(h1w, hv)                                                 \
        }

        for (int it = 0; it < 32; ++it) {
            __syncthreads();
            L1PRE(0, 0)
            L1PRE(1, 1) L1CORE(0)
            L1PRE(2, 0) L1CORE(1)
            L1PRE(3, 1) L1CORE(0)
            L1PRE(4, 0) L1CORE(1)
            L1PRE(5, 1) L1CORE(0)
            L1PRE(6, 0) L1CORE(1)
            L1PRE(7, 1) L1CORE(0)
            L1CORE(1)
            __syncthreads();
            L1PRE(8, 0)
            L1PRE(9,  1) L1CORE(0)
            L1PRE(10, 0) L1CORE(1)
            L1PRE(11, 1) L1CORE(0)
            L1PRE(12, 0) L1CORE(1)
            L1PRE(13, 1) L1CORE(0)
            L1PRE(14, 0) L1CORE(1)
            L1PRE(15, 1) L1CORE(0)
            L1CORE(1)
        }
#undef L1PRE
#undef L1CORE

        if (unitlane) fcb[eIw][ju] = hj * wfc;
        __syncthreads();
        if (l20 == 0 && lane < 40) {
            float p = bfc[0];
            #pragma unroll
            for (int k = 0; k < 10; ++k) p += fcb[eIw][k];
            out[e] = p;
        }
        if (unitlane) {
            out[4096 + 40960  + e * 10 + ju] = hj;   // h1_T
            out[4096 + 122880 + e * 10 + ju] = cc;   // c1_T
        }
    }
}

extern "C" void kernel_launch(void* const* d_in, const int* in_sizes, int n_in,
                              void* d_out, int out_size, void* d_ws, size_t ws_size,
                              hipStream_t stream) {
    const float* x    = (const float*)d_in[0];
    const float* hid  = (const float*)d_in[1];
    const float* cel  = (const float*)d_in[2];
    const float* Wih0 = (const float*)d_in[3];
    const float* Whh0 = (const float*)d_in[4];
    const float* bih0 = (const float*)d_in[5];
    const float* bhh0 = (const float*)d_in[6];
    const float* Wih1 = (const float*)d_in[7];
    const float* Whh1 = (const float*)d_in[8];
    const float* bih1 = (const float*)d_in[9];
    const float* bhh1 = (const float*)d_in[10];
    const float* Wfc  = (const float*)d_in[11];
    const float* bfc  = (const float*)d_in[12];

    // 1024 blocks x 256 thr (2 L0 + 2 L1 waves, 4 elems/block) = 4096 exact
    hipLaunchKernelGGL(lstm2_r16, dim3(1024), dim3(256), 0, stream,
                       x, hid, cel, Wih0, Whh0, bih0, bhh0,
                       Wih1, Whh1, bih1, bhh1, Wfc, bfc,
                       (float*)d_out);
}

// Round 18
// 159.603 us; speedup vs baseline: 1.2526x; 1.2526x over previous
//
#include <hip/hip_runtime.h>

// 2-layer LSTM, B=4096, S=512, F=8, H=10 + FC(10->1) on last step.
// R17 = R10 config (best measured: 683x256, 3 elem/wave, 20-lane scheme)
// with self-stall fixes:
//  - L1 3-stage pipeline RD(s+2) || DOTS(s+1) || CORE(s): slot read issued
//    two bodies before its dots (R10 exposed ~110cyc lgkm per step in PRE).
//  - 32-slot h0 buffer, barrier every 16 steps (64 -> 32 barriers).
//  - L0 x refills: bumped pointer + compile-time immediate offsets, last
//    iteration peeled (kills per-step min-clamp + 64b address math).
// Per-step scheme unchanged (R10): lane l20 owns gate rows rA=l20, rB=20+l20;
// unified act alpha*rcp(1+exp2(-a))+beta; ig lane-local; sf,so via 2 bperms;
// distance-1 x-dot pipeline; TBAA-safe packed LDS row reads.

typedef __fp16 v2h __attribute__((ext_vector_type(2)));
typedef __fp16 v8h __attribute__((ext_vector_type(8)));
struct h4 { v2h a, b, c, d; };

#define L2E 1.4426950408889634f

__device__ __forceinline__ v2h pkh(float a, float b) {
    return __builtin_amdgcn_cvt_pkrtz(a, b);
}
__device__ __forceinline__ float bpermf(int baddr, float v) {
    int r = __builtin_amdgcn_ds_bpermute(baddr, __builtin_bit_cast(int, v));
    return __builtin_bit_cast(float, r);
}

#define SIGM(a)  __builtin_amdgcn_rcpf(1.0f + __builtin_amdgcn_exp2f(-(a)))
#define TANHP(a) fmaf(-2.0f, __builtin_amdgcn_rcpf(1.0f + __builtin_amdgcn_exp2f(a)), 1.0f)
#define DOT2(acc, w, v) (acc) = __builtin_amdgcn_fdot2((w), (v), (acc), false)

// TBAA-safe packed row read (PTR __fp16*, 16B aligned): 10 halves
#define READROW(PTR, H)                                                      \
    { v8h w0_ = *(const v8h*)(PTR);                                          \
      v2h w1_ = *(const v2h*)((PTR) + 8);                                    \
      h4 q_ = __builtin_bit_cast(h4, w0_);                                   \
      H[0]=q_.a; H[1]=q_.b; H[2]=q_.c; H[3]=q_.d; H[4]=w1_; }

__global__ __launch_bounds__(256, 2)
void lstm2_r17(const float* __restrict__ x,
               const float* __restrict__ hid,
               const float* __restrict__ cel,
               const float* __restrict__ Wih0, const float* __restrict__ Whh0,
               const float* __restrict__ bih0, const float* __restrict__ bhh0,
               const float* __restrict__ Wih1, const float* __restrict__ Whh1,
               const float* __restrict__ bih1, const float* __restrict__ bhh1,
               const float* __restrict__ Wfc,  const float* __restrict__ bfc,
               float* __restrict__ out)
{
    __shared__ __attribute__((aligned(16))) __fp16 h0buf[32][6][24]; // 9.2KB
    __shared__ __attribute__((aligned(16))) __fp16 h1buf[6][24];
    __shared__ float fcb[6][10];

    const int tid  = threadIdx.x;
    const int lane = tid & 63;
    const int uwid = __builtin_amdgcn_readfirstlane(tid >> 6);
    int grp = lane / 20;
    int l20 = lane - grp * 20;
    if (lane >= 60) { grp = 2; l20 = 19; }   // pad lanes duplicate lane 59
    const int  ju       = (l20 < 10) ? l20 : l20 - 10;  // unit index
    const bool unitlane = (l20 < 10);
    const int  eIw = (uwid & 1) * 3 + grp;   // element in block, 0..5
    const int  e   = blockIdx.x * 6 + eIw;   // 683*6 = 4098 (2 pad)
    const int  ec  = (e < 4095) ? e : 4095;  // clamped for loads
    const int  baddr = ((l20 < 10) ? (lane + 10) : lane) * 4;  // bpermute src

    const float alpha2 = unitlane ? 2.0f : 1.0f;   // rowB act: tanh vs sigma
    const float beta2  = unitlane ? -1.0f : 0.0f;
    const float scB    = unitlane ? 2.0f * L2E : L2E;
    const int   rA = l20, rB = 20 + l20;

    if (uwid < 2) {
        // ================= LAYER-0 (producer) waves =================
        v2h wxA[4], wxB[4], whA[5], whB[5];
        #pragma unroll
        for (int k = 0; k < 4; ++k) {
            wxA[k] = pkh(Wih0[rA*8+2*k]*L2E, Wih0[rA*8+2*k+1]*L2E);
            wxB[k] = pkh(Wih0[rB*8+2*k]*scB, Wih0[rB*8+2*k+1]*scB);
        }
        #pragma unroll
        for (int k = 0; k < 5; ++k) {
            whA[k] = pkh(Whh0[rA*10+2*k]*L2E, Whh0[rA*10+2*k+1]*L2E);
            whB[k] = pkh(Whh0[rB*10+2*k]*scB, Whh0[rB*10+2*k+1]*scB);
        }
        const float bA = (bih0[rA] + bhh0[rA]) * L2E;
        const float bB = (bih0[rB] + bhh0[rB]) * scB;

        v2h hv[5];
        #pragma unroll
        for (int k = 0; k < 5; ++k) hv[k] = pkh(hid[ec*10+2*k], hid[ec*10+2*k+1]);
        float cc = cel[ec * 10 + ju];
        float hj = 0.0f;

        __fp16* const wbase = &h0buf[0][eIw][0];   // slot stride 144 halves
        __fp16* const wlane = wbase + l20;

        const float4* __restrict__ xp4 = reinterpret_cast<const float4*>(x + (size_t)ec * 4096);
        float4 xb0[2], xb1[2], xb2[2], xb3[2];
        xb0[0]=xp4[0]; xb0[1]=xp4[1];  xb1[0]=xp4[2]; xb1[1]=xp4[3];
        xb2[0]=xp4[4]; xb2[1]=xp4[5];  xb3[0]=xp4[6]; xb3[1]=xp4[7];

        float axA[2], axB[2];
        // prologue: ax(step 0) from xb0, then refill xb0 <- x[4]
        {
            v2h x0=pkh(xb0[0].x,xb0[0].y), x1=pkh(xb0[0].z,xb0[0].w);
            v2h x2=pkh(xb0[1].x,xb0[1].y), x3=pkh(xb0[1].z,xb0[1].w);
            xb0[0]=xp4[8]; xb0[1]=xp4[9];
            float nA=bA, nB=bB;
            DOT2(nA,wxA[0],x0); DOT2(nB,wxB[0],x0);
            DOT2(nA,wxA[1],x1); DOT2(nB,wxB[1],x1);
            DOT2(nA,wxA[2],x2); DOT2(nB,wxB[2],x2);
            DOT2(nA,wxA[3],x3); DOT2(nB,wxB[3],x3);
            axA[0]=nA; axB[0]=nB;
        }

// Body S of a 32-step window (step s = 32*it + S): filler = ax(s+1) from XB
// (= x[s+1]); refill XB <- xr[2*(S+5)] (imm offset); current step uses
// ax[PC]; write h slot S; packed readback.
#define L0STEP(S, XB, DOREF, PC, PN)                                         \
        {                                                                    \
            v2h x0=pkh(XB[0].x,XB[0].y), x1=pkh(XB[0].z,XB[0].w);            \
            v2h x2=pkh(XB[1].x,XB[1].y), x3=pkh(XB[1].z,XB[1].w);            \
            if (DOREF) { XB[0]=xr[2*((S)+5)]; XB[1]=xr[2*((S)+5)+1]; }       \
            float nA=bA, nB=bB;                                              \
            DOT2(nA,wxA[0],x0); DOT2(nB,wxB[0],x0);                          \
            DOT2(nA,wxA[1],x1); DOT2(nB,wxB[1],x1);                          \
            DOT2(nA,wxA[2],x2); DOT2(nB,wxB[2],x2);                          \
            DOT2(nA,wxA[3],x3); DOT2(nB,wxB[3],x3);                          \
            axA[PN]=nA; axB[PN]=nB;                                          \
            float aA=axA[PC], aB=axB[PC];                                    \
            DOT2(aA,whA[0],hv[0]); DOT2(aB,whB[0],hv[0]);                    \
            DOT2(aA,whA[1],hv[1]); DOT2(aB,whB[1],hv[1]);                    \
            DOT2(aA,whA[2],hv[2]); DOT2(aB,whB[2],hv[2]);                    \
            DOT2(aA,whA[3],hv[3]); DOT2(aB,whB[3],hv[3]);                    \
            DOT2(aA,whA[4],hv[4]); DOT2(aB,whB[4],hv[4]);                    \
            float r1 = SIGM(aA);                                             \
            float r2 = __builtin_amdgcn_rcpf(1.0f + __builtin_amdgcn_exp2f(-aB)); \
            float act2 = fmaf(alpha2, r2, beta2);                            \
            float ig = r1 * act2;                                            \
            float sf = bpermf(baddr, r1);                                    \
            float so = bpermf(baddr, act2);                                  \
            cc = fmaf(sf, cc, ig);                                           \
            hj = so * TANHP((2.0f*L2E) * cc);                                \
            wlane[(S)*144] = (__fp16)hj;                                     \
            READROW(wbase + (S)*144, hv)                                     \
        }

#define L0HALF1(RF)                                                          \
            L0STEP(0,  xb1, 1,  0, 1)  L0STEP(1,  xb2, 1,  1, 0)             \
            L0STEP(2,  xb3, 1,  0, 1)  L0STEP(3,  xb0, 1,  1, 0)             \
            L0STEP(4,  xb1, 1,  0, 1)  L0STEP(5,  xb2, 1,  1, 0)             \
            L0STEP(6,  xb3, 1,  0, 1)  L0STEP(7,  xb0, 1,  1, 0)             \
            L0STEP(8,  xb1, 1,  0, 1)  L0STEP(9,  xb2, 1,  1, 0)             \
            L0STEP(10, xb3, 1,  0, 1)  L0STEP(11, xb0, 1,  1, 0)             \
            L0STEP(12, xb1, 1,  0, 1)  L0STEP(13, xb2, 1,  1, 0)             \
            L0STEP(14, xb3, 1,  0, 1)  L0STEP(15, xb0, RF, 1, 0)

        const float4* __restrict__ xr = xp4;
        for (int it = 0; it < 15; ++it) {
            L0HALF1(1)
            __syncthreads();
            L0STEP(16, xb1, 1, 0, 1)  L0STEP(17, xb2, 1, 1, 0)
            L0STEP(18, xb3, 1, 0, 1)  L0STEP(19, xb0, 1, 1, 0)
            L0STEP(20, xb1, 1, 0, 1)  L0STEP(21, xb2, 1, 1, 0)
            L0STEP(22, xb3, 1, 0, 1)  L0STEP(23, xb0, 1, 1, 0)
            L0STEP(24, xb1, 1, 0, 1)  L0STEP(25, xb2, 1, 1, 0)
            L0STEP(26, xb3, 1, 0, 1)  L0STEP(27, xb0, 1, 1, 0)
            L0STEP(28, xb1, 1, 0, 1)  L0STEP(29, xb2, 1, 1, 0)
            L0STEP(30, xb3, 1, 0, 1)  L0STEP(31, xb0, 1, 1, 0)
            __syncthreads();
            xr += 64;
        }
        // peeled it=15 (steps 480..511): refill only while target <= x[511]
        L0HALF1(1)
        __syncthreads();
        L0STEP(16, xb1, 1, 0, 1)  L0STEP(17, xb2, 1, 1, 0)
        L0STEP(18, xb3, 1, 0, 1)  L0STEP(19, xb0, 1, 1, 0)
        L0STEP(20, xb1, 1, 0, 1)  L0STEP(21, xb2, 1, 1, 0)
        L0STEP(22, xb3, 1, 0, 1)  L0STEP(23, xb0, 1, 1, 0)
        L0STEP(24, xb1, 1, 0, 1)  L0STEP(25, xb2, 1, 1, 0)
        L0STEP(26, xb3, 1, 0, 1)  L0STEP(27, xb0, 0, 1, 0)
        L0STEP(28, xb1, 0, 0, 1)  L0STEP(29, xb2, 0, 1, 0)
        L0STEP(30, xb3, 0, 0, 1)  L0STEP(31, xb0, 0, 1, 0)
        __syncthreads();
#undef L0STEP
#undef L0HALF1

        __syncthreads();   // pair with L1's FC epilogue barrier
        if (unitlane && e < 4096) {
            out[4096          + e * 10 + ju] = hj;   // h0_T
            out[4096 + 81920  + e * 10 + ju] = cc;   // c0_T
        }

    } else {
        // ================= LAYER-1 (consumer) waves =================
        v2h wiA[5], wiB[5], whA[5], whB[5];
        #pragma unroll
        for (int k = 0; k < 5; ++k) {
            wiA[k] = pkh(Wih1[rA*10+2*k]*L2E, Wih1[rA*10+2*k+1]*L2E);
            wiB[k] = pkh(Wih1[rB*10+2*k]*scB, Wih1[rB*10+2*k+1]*scB);
            whA[k] = pkh(Whh1[rA*10+2*k]*L2E, Whh1[rA*10+2*k+1]*L2E);
            whB[k] = pkh(Whh1[rB*10+2*k]*scB, Whh1[rB*10+2*k+1]*scB);
        }
        const float bA = (bih1[rA] + bhh1[rA]) * L2E;
        const float bB = (bih1[rB] + bhh1[rB]) * scB;
        const float wfc = Wfc[ju];

        v2h hv[5];
        #pragma unroll
        for (int k = 0; k < 5; ++k) hv[k] = pkh(hid[40960+ec*10+2*k], hid[40960+ec*10+2*k+1]);
        float cc = cel[40960 + ec * 10 + ju];
        float hj = 0.0f;

        const __fp16* const rbase = &h0buf[0][eIw][0];   // slot stride 144 halves
        __fp16* const h1w  = &h1buf[eIw][0];
        __fp16* const h1wl = h1w + l20;

        v2h prA[5], prB[5];
        float ax0A, ax0B, ax1A, ax1B;

// RD: issue packed slot read. DOTS: bias + 5 input-row dots from PR -> AX.
// CORE: 5 h-dots from AX, acts, c/h, h1 write+readback.
#define L1RD(PR, S)  READROW(rbase + (S)*144, PR)
#define L1DOTS(PR, AXA, AXB)                                                 \
        {                                                                    \
            float nA=bA, nB=bB;                                              \
            DOT2(nA,wiA[0],PR[0]); DOT2(nB,wiB[0],PR[0]);                    \
            DOT2(nA,wiA[1],PR[1]); DOT2(nB,wiB[1],PR[1]);                    \
            DOT2(nA,wiA[2],PR[2]); DOT2(nB,wiB[2],PR[2]);                    \
            DOT2(nA,wiA[3],PR[3]); DOT2(nB,wiB[3],PR[3]);                    \
            DOT2(nA,wiA[4],PR[4]); DOT2(nB,wiB[4],PR[4]);                    \
            AXA=nA; AXB=nB;                                                  \
        }
#define L1CORE(AXA, AXB)                                                     \
        {                                                                    \
            float aA=AXA, aB=AXB;                                            \
            DOT2(aA,whA[0],hv[0]); DOT2(aB,whB[0],hv[0]);                    \
            DOT2(aA,whA[1],hv[1]); DOT2(aB,whB[1],hv[1]);                    \
            DOT2(aA,whA[2],hv[2]); DOT2(aB,whB[2],hv[2]);                    \
            DOT2(aA,whA[3],hv[3]); DOT2(aB,whB[3],hv[3]);                    \
            DOT2(aA,whA[4],hv[4]); DOT2(aB,whB[4],hv[4]);                    \
            float r1 = SIGM(aA);                                             \
            float r2 = __builtin_amdgcn_rcpf(1.0f + __builtin_amdgcn_exp2f(-aB)); \
            float act2 = fmaf(alpha2, r2, beta2);                            \
            float ig = r1 * act2;                                            \
            float sf = bpermf(baddr, r1);                                    \
            float so = bpermf(baddr, act2);                                  \
            cc = fmaf(sf, cc, ig);                                           \
            hj = so * TANHP((2.0f*L2E) * cc);                                \
            h1wl[0] = (__fp16)hj;                                            \
            READROW(h1w, hv)                                                 \
        }

// 16-step half window over slots W..W+15, 3-stage pipeline.
#define L1HALF(W)                                                            \
        L1RD(prA, (W)+0)                                                     \
        L1RD(prB, (W)+1)  L1DOTS(prA, ax0A, ax0B)                            \
        L1RD(prA, (W)+2)  L1DOTS(prB, ax1A, ax1B)  L1CORE(ax0A, ax0B)        \
        L1RD(prB, (W)+3)  L1DOTS(prA, ax0A, ax0B)  L1CORE(ax1A, ax1B)        \
        L1RD(prA, (W)+4)  L1DOTS(prB, ax1A, ax1B)  L1CORE(ax0A, ax0B)        \
        L1RD(prB, (W)+5)  L1DOTS(prA, ax0A, ax0B)  L1CORE(ax1A, ax1B)        \
        L1RD(prA, (W)+6)  L1DOTS(prB, ax1A, ax1B)  L1CORE(ax0A, ax0B)        \
        L1RD(prB, (W)+7)  L1DOTS(prA, ax0A, ax0B)  L1CORE(ax1A, ax1B)        \
        L1RD(prA, (W)+8)  L1DOTS(prB, ax1A, ax1B)  L1CORE(ax0A, ax0B)        \
        L1RD(prB, (W)+9)  L1DOTS(prA, ax0A, ax0B)  L1CORE(ax1A, ax1B)        \
        L1RD(prA, (W)+10) L1DOTS(prB, ax1A, ax1B)  L1CORE(ax0A, ax0B)        \
        L1RD(prB, (W)+11) L1DOTS(prA, ax0A, ax0B)  L1CORE(ax1A, ax1B)        \
        L1RD(prA, (W)+12) L1DOTS(prB, ax1A, ax1B)  L1CORE(ax0A, ax0B)        \
        L1RD(prB, (W)+13) L1DOTS(prA, ax0A, ax0B)  L1CORE(ax1A, ax1B)        \
        L1RD(prA, (W)+14) L1DOTS(prB, ax1A, ax1B)  L1CORE(ax0A, ax0B)        \
        L1RD(prB, (W)+15) L1DOTS(prA, ax0A, ax0B)  L1CORE(ax1A, ax1B)        \
                          L1DOTS(prB, ax1A, ax1B)  L1CORE(ax0A, ax0B)        \
                                                   L1CORE(ax1A, ax1B)

        for (int it = 0; it < 16; ++it) {
            __syncthreads();
            L1HALF(0)
            __syncthreads();
            L1HALF(16)
        }
#undef L1HALF
#undef L1RD
#undef L1DOTS
#undef L1CORE

        if (unitlane) fcb[eIw][ju] = hj * wfc;
        __syncthreads();
        if (l20 == 0 && e < 4096) {
            float p = bfc[0];
            #pragma unroll
            for (int k = 0; k < 10; ++k) p += fcb[eIw][k];
            out[e] = p;
        }
        if (unitlane && e < 4096) {
            out[4096 + 40960  + e * 10 + ju] = hj;   // h1_T
            out[4096 + 122880 + e * 10 + ju] = cc;   // c1_T
        }
    }
}

extern "C" void kernel_launch(void* const* d_in, const int* in_sizes, int n_in,
                              void* d_out, int out_size, void* d_ws, size_t ws_size,
                              hipStream_t stream) {
    const float* x    = (const float*)d_in[0];
    const float* hid  = (const float*)d_in[1];
    const float* cel  = (const float*)d_in[2];
    const float* Wih0 = (const float*)d_in[3];
    const float* Whh0 = (const float*)d_in[4];
    const float* bih0 = (const float*)d_in[5];
    const float* bhh0 = (const float*)d_in[6];
    const float* Wih1 = (const float*)d_in[7];
    const float* Whh1 = (const float*)d_in[8];
    const float* bih1 = (const float*)d_in[9];
    const float* bhh1 = (const float*)d_in[10];
    const float* Wfc  = (const float*)d_in[11];
    const float* bfc  = (const float*)d_in[12];

    // 683 blocks x 256 thr (2 L0 + 2 L1 waves, 6 elements/block) — R10 grid
    hipLaunchKernelGGL(lstm2_r17, dim3(683), dim3(256), 0, stream,
                       x, hid, cel, Wih0, Whh0, bih0, bhh0,
                       Wih1, Whh1, bih1, bhh1, Wfc, bfc,
                       (float*)d_out);
}

// Round 19
// 155.994 us; speedup vs baseline: 1.2815x; 1.0231x over previous
//
#include <hip/hip_runtime.h>

// 2-layer LSTM, B=4096, S=512, F=8, H=10 + FC(10->1) on last step.
// R18 = R17 with ALL workgroup barriers replaced by per-pair lock-free
// ring handoff (SPSC, 32-slot, LDS flags with release/acquire):
//  - pairs (L0 wave 0 -> L1 wave 2), (L0 wave 1 -> L1 wave 3) independent
//  - producer publishes prog after each 16-step half-window; consumer
//    publishes cons; spin (acquire + s_sleep) only when 32-slot drift hit
//  - waves free-run and DE-PHASE: R10/R16/R17 showed a ~320cyc/step stall
//    residue constant across occupancy because lockstep code + barriers
//    align all resident waves' stalls; decoherence lets cross-wave
//    interleave fill them.
// Per-step scheme unchanged (R10/R17 proven): 20-lane groups, 3 elem/wave,
// rows rA=l20,rB=20+l20, unified act, 2 bperms, distance-1 x-pipeline,
// L1 3-stage RD||DOTS||CORE pipeline, imm-offset x refills.

typedef __fp16 v2h __attribute__((ext_vector_type(2)));
typedef __fp16 v8h __attribute__((ext_vector_type(8)));
struct h4 { v2h a, b, c, d; };

#define L2E 1.4426950408889634f

__device__ __forceinline__ v2h pkh(float a, float b) {
    return __builtin_amdgcn_cvt_pkrtz(a, b);
}
__device__ __forceinline__ float bpermf(int baddr, float v) {
    int r = __builtin_amdgcn_ds_bpermute(baddr, __builtin_bit_cast(int, v));
    return __builtin_bit_cast(float, r);
}
__device__ __forceinline__ void wg_wait_ge(int* flag, int target) {
    while (__hip_atomic_load(flag, __ATOMIC_ACQUIRE, __HIP_MEMORY_SCOPE_WORKGROUP) < target)
        __builtin_amdgcn_s_sleep(2);
}
__device__ __forceinline__ void wg_publish(int* flag, int v, int lane) {
    if (lane == 0)
        __hip_atomic_store(flag, v, __ATOMIC_RELEASE, __HIP_MEMORY_SCOPE_WORKGROUP);
}

#define SIGM(a)  __builtin_amdgcn_rcpf(1.0f + __builtin_amdgcn_exp2f(-(a)))
#define TANHP(a) fmaf(-2.0f, __builtin_amdgcn_rcpf(1.0f + __builtin_amdgcn_exp2f(a)), 1.0f)
#define DOT2(acc, w, v) (acc) = __builtin_amdgcn_fdot2((w), (v), (acc), false)

// TBAA-safe packed row read (PTR __fp16*, 16B aligned): 10 halves
#define READROW(PTR, H)                                                      \
    { v8h w0_ = *(const v8h*)(PTR);                                          \
      v2h w1_ = *(const v2h*)((PTR) + 8);                                    \
      h4 q_ = __builtin_bit_cast(h4, w0_);                                   \
      H[0]=q_.a; H[1]=q_.b; H[2]=q_.c; H[3]=q_.d; H[4]=w1_; }

__global__ __launch_bounds__(256, 2)
void lstm2_r18(const float* __restrict__ x,
               const float* __restrict__ hid,
               const float* __restrict__ cel,
               const float* __restrict__ Wih0, const float* __restrict__ Whh0,
               const float* __restrict__ bih0, const float* __restrict__ bhh0,
               const float* __restrict__ Wih1, const float* __restrict__ Whh1,
               const float* __restrict__ bih1, const float* __restrict__ bhh1,
               const float* __restrict__ Wfc,  const float* __restrict__ bfc,
               float* __restrict__ out)
{
    __shared__ __attribute__((aligned(16))) __fp16 h0buf[32][6][24]; // 9.2KB
    __shared__ __attribute__((aligned(16))) __fp16 h1buf[6][24];
    __shared__ float fcb[6][10];
    __shared__ int s_prog[2];   // producer steps published (per pair)
    __shared__ int s_cons[2];   // consumer steps published (per pair)

    const int tid  = threadIdx.x;
    const int lane = tid & 63;
    const int uwid = __builtin_amdgcn_readfirstlane(tid >> 6);
    int grp = lane / 20;
    int l20 = lane - grp * 20;
    if (lane >= 60) { grp = 2; l20 = 19; }   // pad lanes duplicate lane 59
    const int  ju       = (l20 < 10) ? l20 : l20 - 10;  // unit index
    const bool unitlane = (l20 < 10);
    const int  eIw = (uwid & 1) * 3 + grp;   // element in block, 0..5
    const int  e   = blockIdx.x * 6 + eIw;   // 683*6 = 4098 (2 pad)
    const int  ec  = (e < 4095) ? e : 4095;  // clamped for loads
    const int  pair = uwid & 1;
    const int  baddr = ((l20 < 10) ? (lane + 10) : lane) * 4;  // bpermute src

    const float alpha2 = unitlane ? 2.0f : 1.0f;   // rowB act: tanh vs sigma
    const float beta2  = unitlane ? -1.0f : 0.0f;
    const float scB    = unitlane ? 2.0f * L2E : L2E;
    const int   rA = l20, rB = 20 + l20;

    if (tid < 2) { s_prog[tid] = 0; s_cons[tid] = 0; }
    __syncthreads();   // the ONLY barrier: flag init visibility

    if (uwid < 2) {
        // ================= LAYER-0 (producer) waves =================
        v2h wxA[4], wxB[4], whA[5], whB[5];
        #pragma unroll
        for (int k = 0; k < 4; ++k) {
            wxA[k] = pkh(Wih0[rA*8+2*k]*L2E, Wih0[rA*8+2*k+1]*L2E);
            wxB[k] = pkh(Wih0[rB*8+2*k]*scB, Wih0[rB*8+2*k+1]*scB);
        }
        #pragma unroll
        for (int k = 0; k < 5; ++k) {
            whA[k] = pkh(Whh0[rA*10+2*k]*L2E, Whh0[rA*10+2*k+1]*L2E);
            whB[k] = pkh(Whh0[rB*10+2*k]*scB, Whh0[rB*10+2*k+1]*scB);
        }
        const float bA = (bih0[rA] + bhh0[rA]) * L2E;
        const float bB = (bih0[rB] + bhh0[rB]) * scB;

        v2h hv[5];
        #pragma unroll
        for (int k = 0; k < 5; ++k) hv[k] = pkh(hid[ec*10+2*k], hid[ec*10+2*k+1]);
        float cc = cel[ec * 10 + ju];
        float hj = 0.0f;

        __fp16* const wbase = &h0buf[0][eIw][0];   // slot stride 144 halves
        __fp16* const wlane = wbase + l20;

        const float4* __restrict__ xp4 = reinterpret_cast<const float4*>(x + (size_t)ec * 4096);
        float4 xb0[2], xb1[2], xb2[2], xb3[2];
        xb0[0]=xp4[0]; xb0[1]=xp4[1];  xb1[0]=xp4[2]; xb1[1]=xp4[3];
        xb2[0]=xp4[4]; xb2[1]=xp4[5];  xb3[0]=xp4[6]; xb3[1]=xp4[7];

        float axA[2], axB[2];
        // prologue: ax(step 0) from xb0, then refill xb0 <- x[4]
        {
            v2h x0=pkh(xb0[0].x,xb0[0].y), x1=pkh(xb0[0].z,xb0[0].w);
            v2h x2=pkh(xb0[1].x,xb0[1].y), x3=pkh(xb0[1].z,xb0[1].w);
            xb0[0]=xp4[8]; xb0[1]=xp4[9];
            float nA=bA, nB=bB;
            DOT2(nA,wxA[0],x0); DOT2(nB,wxB[0],x0);
            DOT2(nA,wxA[1],x1); DOT2(nB,wxB[1],x1);
            DOT2(nA,wxA[2],x2); DOT2(nB,wxB[2],x2);
            DOT2(nA,wxA[3],x3); DOT2(nB,wxB[3],x3);
            axA[0]=nA; axB[0]=nB;
        }

#define L0STEP(S, XB, DOREF, PC, PN)                                         \
        {                                                                    \
            v2h x0=pkh(XB[0].x,XB[0].y), x1=pkh(XB[0].z,XB[0].w);            \
            v2h x2=pkh(XB[1].x,XB[1].y), x3=pkh(XB[1].z,XB[1].w);            \
            if (DOREF) { XB[0]=xr[2*((S)+5)]; XB[1]=xr[2*((S)+5)+1]; }       \
            float nA=bA, nB=bB;                                              \
            DOT2(nA,wxA[0],x0); DOT2(nB,wxB[0],x0);                          \
            DOT2(nA,wxA[1],x1); DOT2(nB,wxB[1],x1);                          \
            DOT2(nA,wxA[2],x2); DOT2(nB,wxB[2],x2);                          \
            DOT2(nA,wxA[3],x3); DOT2(nB,wxB[3],x3);                          \
            axA[PN]=nA; axB[PN]=nB;                                          \
            float aA=axA[PC], aB=axB[PC];                                    \
            DOT2(aA,whA[0],hv[0]); DOT2(aB,whB[0],hv[0]);                    \
            DOT2(aA,whA[1],hv[1]); DOT2(aB,whB[1],hv[1]);                    \
            DOT2(aA,whA[2],hv[2]); DOT2(aB,whB[2],hv[2]);                    \
            DOT2(aA,whA[3],hv[3]); DOT2(aB,whB[3],hv[3]);                    \
            DOT2(aA,whA[4],hv[4]); DOT2(aB,whB[4],hv[4]);                    \
            float r1 = SIGM(aA);                                             \
            float r2 = __builtin_amdgcn_rcpf(1.0f + __builtin_amdgcn_exp2f(-aB)); \
            float act2 = fmaf(alpha2, r2, beta2);                            \
            float ig = r1 * act2;                                            \
            float sf = bpermf(baddr, r1);                                    \
            float so = bpermf(baddr, act2);                                  \
            cc = fmaf(sf, cc, ig);                                           \
            hj = so * TANHP((2.0f*L2E) * cc);                                \
            wlane[(S)*144] = (__fp16)hj;                                     \
            READROW(wbase + (S)*144, hv)                                     \
        }

#define L0HALF1(RF)                                                          \
            L0STEP(0,  xb1, 1,  0, 1)  L0STEP(1,  xb2, 1,  1, 0)             \
            L0STEP(2,  xb3, 1,  0, 1)  L0STEP(3,  xb0, 1,  1, 0)             \
            L0STEP(4,  xb1, 1,  0, 1)  L0STEP(5,  xb2, 1,  1, 0)             \
            L0STEP(6,  xb3, 1,  0, 1)  L0STEP(7,  xb0, 1,  1, 0)             \
            L0STEP(8,  xb1, 1,  0, 1)  L0STEP(9,  xb2, 1,  1, 0)             \
            L0STEP(10, xb3, 1,  0, 1)  L0STEP(11, xb0, 1,  1, 0)             \
            L0STEP(12, xb1, 1,  0, 1)  L0STEP(13, xb2, 1,  1, 0)             \
            L0STEP(14, xb3, 1,  0, 1)  L0STEP(15, xb0, RF, 1, 0)

        const float4* __restrict__ xr = xp4;
        for (int it = 0; it < 15; ++it) {
            wg_wait_ge(&s_cons[pair], 32*it - 16);
            L0HALF1(1)
            wg_publish(&s_prog[pair], 32*it + 16, lane);
            wg_wait_ge(&s_cons[pair], 32*it);
            L0STEP(16, xb1, 1, 0, 1)  L0STEP(17, xb2, 1, 1, 0)
            L0STEP(18, xb3, 1, 0, 1)  L0STEP(19, xb0, 1, 1, 0)
            L0STEP(20, xb1, 1, 0, 1)  L0STEP(21, xb2, 1, 1, 0)
            L0STEP(22, xb3, 1, 0, 1)  L0STEP(23, xb0, 1, 1, 0)
            L0STEP(24, xb1, 1, 0, 1)  L0STEP(25, xb2, 1, 1, 0)
            L0STEP(26, xb3, 1, 0, 1)  L0STEP(27, xb0, 1, 1, 0)
            L0STEP(28, xb1, 1, 0, 1)  L0STEP(29, xb2, 1, 1, 0)
            L0STEP(30, xb3, 1, 0, 1)  L0STEP(31, xb0, 1, 1, 0)
            wg_publish(&s_prog[pair], 32*it + 32, lane);
            xr += 64;
        }
        // peeled it=15 (steps 480..511): refill only while target <= x[511]
        wg_wait_ge(&s_cons[pair], 32*15 - 16);
        L0HALF1(1)
        wg_publish(&s_prog[pair], 496, lane);
        wg_wait_ge(&s_cons[pair], 480);
        L0STEP(16, xb1, 1, 0, 1)  L0STEP(17, xb2, 1, 1, 0)
        L0STEP(18, xb3, 1, 0, 1)  L0STEP(19, xb0, 1, 1, 0)
        L0STEP(20, xb1, 1, 0, 1)  L0STEP(21, xb2, 1, 1, 0)
        L0STEP(22, xb3, 1, 0, 1)  L0STEP(23, xb0, 1, 1, 0)
        L0STEP(24, xb1, 1, 0, 1)  L0STEP(25, xb2, 1, 1, 0)
        L0STEP(26, xb3, 1, 0, 1)  L0STEP(27, xb0, 0, 1, 0)
        L0STEP(28, xb1, 0, 0, 1)  L0STEP(29, xb2, 0, 1, 0)
        L0STEP(30, xb3, 0, 0, 1)  L0STEP(31, xb0, 0, 1, 0)
        wg_publish(&s_prog[pair], 512, lane);
#undef L0STEP
#undef L0HALF1

        if (unitlane && e < 4096) {
            out[4096          + e * 10 + ju] = hj;   // h0_T
            out[4096 + 81920  + e * 10 + ju] = cc;   // c0_T
        }

    } else {
        // ================= LAYER-1 (consumer) waves =================
        v2h wiA[5], wiB[5], whA[5], whB[5];
        #pragma unroll
        for (int k = 0; k < 5; ++k) {
            wiA[k] = pkh(Wih1[rA*10+2*k]*L2E, Wih1[rA*10+2*k+1]*L2E);
            wiB[k] = pkh(Wih1[rB*10+2*k]*scB, Wih1[rB*10+2*k+1]*scB);
            whA[k] = pkh(Whh1[rA*10+2*k]*L2E, Whh1[rA*10+2*k+1]*L2E);
            whB[k] = pkh(Whh1[rB*10+2*k]*scB, Whh1[rB*10+2*k+1]*scB);
        }
        const float bA = (bih1[rA] + bhh1[rA]) * L2E;
        const float bB = (bih1[rB] + bhh1[rB]) * scB;
        const float wfc = Wfc[ju];

        v2h hv[5];
        #pragma unroll
        for (int k = 0; k < 5; ++k) hv[k] = pkh(hid[40960+ec*10+2*k], hid[40960+ec*10+2*k+1]);
        float cc = cel[40960 + ec * 10 + ju];
        float hj = 0.0f;

        const __fp16* const rbase = &h0buf[0][eIw][0];   // slot stride 144 halves
        __fp16* const h1w  = &h1buf[eIw][0];
        __fp16* const h1wl = h1w + l20;

        v2h prA[5], prB[5];
        float ax0A, ax0B, ax1A, ax1B;

#define L1RD(PR, S)  READROW(rbase + (S)*144, PR)
#define L1DOTS(PR, AXA, AXB)                                                 \
        {                                                                    \
            float nA=bA, nB=bB;                                              \
            DOT2(nA,wiA[0],PR[0]); DOT2(nB,wiB[0],PR[0]);                    \
            DOT2(nA,wiA[1],PR[1]); DOT2(nB,wiB[1],PR[1]);                    \
            DOT2(nA,wiA[2],PR[2]); DOT2(nB,wiB[2],PR[2]);                    \
            DOT2(nA,wiA[3],PR[3]); DOT2(nB,wiB[3],PR[3]);                    \
            DOT2(nA,wiA[4],PR[4]); DOT2(nB,wiB[4],PR[4]);                    \
            AXA=nA; AXB=nB;                                                  \
        }
#define L1CORE(AXA, AXB)                                                     \
        {                                                                    \
            float aA=AXA, aB=AXB;                                            \
            DOT2(aA,whA[0],hv[0]); DOT2(aB,whB[0],hv[0]);                    \
            DOT2(aA,whA[1],hv[1]); DOT2(aB,whB[1],hv[1]);                    \
            DOT2(aA,whA[2],hv[2]); DOT2(aB,whB[2],hv[2]);                    \
            DOT2(aA,whA[3],hv[3]); DOT2(aB,whB[3],hv[3]);                    \
            DOT2(aA,whA[4],hv[4]); DOT2(aB,whB[4],hv[4]);                    \
            float r1 = SIGM(aA);                                             \
            float r2 = __builtin_amdgcn_rcpf(1.0f + __builtin_amdgcn_exp2f(-aB)); \
            float act2 = fmaf(alpha2, r2, beta2);                            \
            float ig = r1 * act2;                                            \
            float sf = bpermf(baddr, r1);                                    \
            float so = bpermf(baddr, act2);                                  \
            cc = fmaf(sf, cc, ig);                                           \
            hj = so * TANHP((2.0f*L2E) * cc);                                \
            h1wl[0] = (__fp16)hj;                                            \
            READROW(h1w, hv)                                                 \
        }

#define L1HALF(W)                                                            \
        L1RD(prA, (W)+0)                                                     \
        L1RD(prB, (W)+1)  L1DOTS(prA, ax0A, ax0B)                            \
        L1RD(prA, (W)+2)  L1DOTS(prB, ax1A, ax1B)  L1CORE(ax0A, ax0B)        \
        L1RD(prB, (W)+3)  L1DOTS(prA, ax0A, ax0B)  L1CORE(ax1A, ax1B)        \
        L1RD(prA, (W)+4)  L1DOTS(prB, ax1A, ax1B)  L1CORE(ax0A, ax0B)        \
        L1RD(prB, (W)+5)  L1DOTS(prA, ax0A, ax0B)  L1CORE(ax1A, ax1B)        \
        L1RD(prA, (W)+6)  L1DOTS(prB, ax1A, ax1B)  L1CORE(ax0A, ax0B)        \
        L1RD(prB, (W)+7)  L1DOTS(prA, ax0A, ax0B)  L1CORE(ax1A, ax1B)        \
        L1RD(prA, (W)+8)  L1DOTS(prB, ax1A, ax1B)  L1CORE(ax0A, ax0B)        \
        L1RD(prB, (W)+9)  L1DOTS(prA, ax0A, ax0B)  L1CORE(ax1A, ax1B)        \
        L1RD(prA, (W)+10) L1DOTS(prB, ax1A, ax1B)  L1CORE(ax0A, ax0B)        \
        L1RD(prB, (W)+11) L1DOTS(prA, ax0A, ax0B)  L1CORE(ax1A, ax1B)        \
        L1RD(prA, (W)+12) L1DOTS(prB, ax1A, ax1B)  L1CORE(ax0A, ax0B)        \
        L1RD(prB, (W)+13) L1DOTS(prA, ax0A, ax0B)  L1CORE(ax1A, ax1B)        \
        L1RD(prA, (W)+14) L1DOTS(prB, ax1A, ax1B)  L1CORE(ax0A, ax0B)        \
        L1RD(prB, (W)+15) L1DOTS(prA, ax0A, ax0B)  L1CORE(ax1A, ax1B)        \
                          L1DOTS(prB, ax1A, ax1B)  L1CORE(ax0A, ax0B)        \
                                                   L1CORE(ax1A, ax1B)

        for (int it = 0; it < 16; ++it) {
            wg_wait_ge(&s_prog[pair], 32*it + 16);
            L1HALF(0)
            wg_publish(&s_cons[pair], 32*it + 16, lane);
            wg_wait_ge(&s_prog[pair], 32*it + 32);
            L1HALF(16)
            wg_publish(&s_cons[pair], 32*it + 32, lane);
        }
#undef L1HALF
#undef L1RD
#undef L1DOTS
#undef L1CORE

        if (unitlane) fcb[eIw][ju] = hj * wfc;   // same-wave DS, in-order
        if (l20 == 0 && e < 4096) {
            float p = bfc[0];
            #pragma unroll
            for (int k = 0; k < 10; ++k) p += fcb[eIw][k];
            out[e] = p;
        }
        if (unitlane && e < 4096) {
            out[4096 + 40960  + e * 10 + ju] = hj;   // h1_T
            out[4096 + 122880 + e * 10 + ju] = cc;   // c1_T
        }
    }
}

extern "C" void kernel_launch(void* const* d_in, const int* in_sizes, int n_in,
                              void* d_out, int out_size, void* d_ws, size_t ws_size,
                              hipStream_t stream) {
    const float* x    = (const float*)d_in[0];
    const float* hid  = (const float*)d_in[1];
    const float* cel  = (const float*)d_in[2];
    const float* Wih0 = (const float*)d_in[3];
    const float* Whh0 = (const float*)d_in[4];
    const float* bih0 = (const float*)d_in[5];
    const float* bhh0 = (const float*)d_in[6];
    const float* Wih1 = (const float*)d_in[7];
    const float* Whh1 = (const float*)d_in[8];
    const float* bih1 = (const float*)d_in[9];
    const float* bhh1 = (const float*)d_in[10];
    const float* Wfc  = (const float*)d_in[11];
    const float* bfc  = (const float*)d_in[12];

    // 683 blocks x 256 thr (2 L0 + 2 L1 waves, 6 elements/block)
    hipLaunchKernelGGL(lstm2_r18, dim3(683), dim3(256), 0, stream,
                       x, hid, cel, Wih0, Whh0, bih0, bhh0,
                       Wih1, Whh1, bih1, bhh1, Wfc, bfc,
                       (float*)d_out);
}